// Round 9
// baseline (496.049 us; speedup 1.0000x reference)
//
#include <hip/hip_runtime.h>
#include <stdint.h>

typedef unsigned short u16;
typedef __bf16 bfv8 __attribute__((ext_vector_type(8)));
typedef float f32x4 __attribute__((ext_vector_type(4)));
typedef unsigned short u16x8 __attribute__((ext_vector_type(8)));

#define DI __device__ __forceinline__

DI u16 f2bf(float f) {
  union { float f; unsigned u; } c; c.f = f;
  unsigned r = c.u + 0x7FFFu + ((c.u >> 16) & 1u);
  return (u16)(r >> 16);
}
DI float bf2f(u16 b) {
  union { unsigned u; float f; } c; c.u = ((unsigned)b) << 16;
  return c.f;
}

enum { EPI_BF16 = 0, EPI_RELU2 = 1, EPI_ADDF32 = 2, EPI_QK = 3 };

#define GLDS(g, l)                                                              \
  __builtin_amdgcn_global_load_lds((const __attribute__((address_space(1))) void*)(g), \
                                   (__attribute__((address_space(3))) void*)(l), 16, 0, 0)

#define VMCNT_BAR(N)                                        \
  do {                                                      \
    asm volatile("s_waitcnt vmcnt(" #N ")" ::: "memory");   \
    __builtin_amdgcn_sched_barrier(0);                      \
    __builtin_amdgcn_s_barrier();                           \
    __builtin_amdgcn_sched_barrier(0);                      \
  } while (0)

#define BAR_ONLY()                                          \
  do {                                                      \
    __builtin_amdgcn_sched_barrier(0);                      \
    __builtin_amdgcn_s_barrier();                           \
    __builtin_amdgcn_sched_barrier(0);                      \
  } while (0)

// C[m,n] = sum_k A[m,k]*B[n,k]. Tile 128x128, BK=64, 512 thr (8 waves 2Mx4N),
// 2-stage double-buffered LDS (64 KB -> 2 blocks/CU) + counted vmcnt(4) + setprio.
template <int EPI, bool KSPLIT>
__global__ __launch_bounds__(512, 4) void gemm128(
    const u16* __restrict__ Aq, const u16* __restrict__ Akv, int asplit,
    long a1q, long a1r, int lda1,
    const u16* __restrict__ A2, int lda2,
    const u16* __restrict__ B1, long b1q, long b1r, int ldb1,
    const u16* __restrict__ B2, long b2q, long b2r, int ldb2,
    int K, int ksp,
    void* __restrict__ Cv, long cq, long cr, int ldc,
    const float* __restrict__ extra, long eq, int lde,
    float scale)
{
  constexpr int NJ = 2;
  constexpr int SS = 16384;
  __shared__ __align__(16) u16 lds[2 * SS];   // 64 KB
  const int tid = threadIdx.x;
  const int wid = tid >> 6, lane = tid & 63;

  const int gx = gridDim.x, gy = gridDim.y;
  const int nwg = gx * gy * (int)gridDim.z;
  const int flat = blockIdx.x + gx * (blockIdx.y + gy * blockIdx.z);
  const int q = nwg >> 3, r = nwg & 7;
  const int xcd = flat & 7, idx = flat >> 3;
  const int wg = (xcd < r ? xcd * (q + 1) : r * (q + 1) + (xcd - r) * q) + idx;
  const int bx = wg % gx;
  const int tmp = wg / gx;
  const int by = tmp % gy;
  const int bz = tmp / gy;

  const long zq = bz >> 2, zr = bz & 3;
  const int m0 = by * 128, n0 = bx * 128;
  const u16* Ab = ((n0 >= asplit) ? Akv : Aq) + zq * a1q + zr * a1r;
  const u16* Bb = B1 + zq * b1q + zr * b1r;
  const u16* B2b = KSPLIT ? (B2 + zq * b2q + zr * b2r) : (const u16*)nullptr;
  const int wm = (wid >> 2) * 64, wn = (wid & 3) * 32;
  const int fr = lane & 15, fq = lane >> 4;

  f32x4 acc[4][NJ];
#pragma unroll
  for (int i = 0; i < 4; ++i)
#pragma unroll
    for (int j = 0; j < NJ; ++j)
      acc[i][j] = (f32x4){0.f, 0.f, 0.f, 0.f};

  const int nt = K >> 6;

  auto STAGE = [&](int tt, int sb) {
    const int k0 = tt << 6;
    u16* Ld = &lds[sb * SS];
    const u16* Asrc; int la; const u16* Bsrc; int lb;
    if (!KSPLIT || k0 < ksp) { Asrc = Ab + k0; la = lda1; Bsrc = Bb + k0; lb = ldb1; }
    else { Asrc = A2 + (k0 - ksp); la = lda2; Bsrc = B2b + (k0 - ksp); lb = ldb2; }
#pragma unroll
    for (int l = 0; l < 2; ++l) {
      int idx2 = (l << 9) + tid;
      int row = idx2 >> 3;
      int sc = ((idx2 & 7) ^ (row & 7)) << 3;
      GLDS(Asrc + (size_t)(m0 + row) * la + sc,
           Ld + (((l << 3) + wid) << 9));
    }
#pragma unroll
    for (int l = 0; l < 2; ++l) {
      int idx2 = (l << 9) + tid;
      int row = idx2 >> 3;
      int sc = ((idx2 & 7) ^ (row & 7)) << 3;
      GLDS(Bsrc + (size_t)(n0 + row) * lb + sc,
           Ld + 8192 + (((l << 3) + wid) << 9));
    }
  };

  auto COMPUTE = [&](int cb) {
    const u16* As = &lds[cb * SS];
    const u16* Bs = As + 8192;
#pragma unroll
    for (int ks = 0; ks < 2; ++ks) {
      bfv8 av[4];
#pragma unroll
      for (int i = 0; i < 4; ++i) {
        int ra = wm + i * 16 + fr;
        int ca = (((ks << 2) + fq) ^ (ra & 7)) << 3;
        av[i] = *(const bfv8*)&As[(ra << 6) + ca];
      }
      bfv8 bv[2];
#pragma unroll
      for (int j = 0; j < 2; ++j) {
        int rb = wn + (j << 4) + fr;
        int cb2 = (((ks << 2) + fq) ^ (rb & 7)) << 3;
        bv[j] = *(const bfv8*)&Bs[(rb << 6) + cb2];
      }
      __builtin_amdgcn_s_setprio(1);
#pragma unroll
      for (int i = 0; i < 4; ++i) {
        acc[i][0] = __builtin_amdgcn_mfma_f32_16x16x32_bf16(av[i], bv[0], acc[i][0], 0, 0, 0);
        acc[i][1] = __builtin_amdgcn_mfma_f32_16x16x32_bf16(av[i], bv[1], acc[i][1], 0, 0, 0);
      }
      __builtin_amdgcn_s_setprio(0);
    }
  };

  STAGE(0, 0);
  STAGE(1, 1);
  VMCNT_BAR(4);
  for (int t = 0; t < nt; ++t) {
    COMPUTE(t & 1);
    BAR_ONLY();
    if (t + 2 < nt) {
      STAGE(t + 2, t & 1);
      VMCNT_BAR(4);
    } else if (t + 1 < nt) {
      VMCNT_BAR(0);
    }
  }

  if constexpr (EPI == EPI_BF16 || EPI == EPI_RELU2) {
    u16* Cb = (u16*)Cv + zq * cq + zr * cr;
#pragma unroll
    for (int i = 0; i < 4; ++i)
#pragma unroll
      for (int j = 0; j < NJ; ++j)
#pragma unroll
        for (int r2 = 0; r2 < 4; ++r2) {
          int row = m0 + wm + i * 16 + (fq << 2) + r2;
          int col = n0 + wn + j * 16 + fr;
          float v = acc[i][j][r2];
          if constexpr (EPI == EPI_RELU2) { v = fmaxf(v, 0.f); v = v * v; }
          Cb[(size_t)row * ldc + col] = f2bf(v);
        }
  } else if constexpr (EPI == EPI_ADDF32) {
    float* Cb = (float*)Cv + zq * cq + zr * cr;
#pragma unroll
    for (int i = 0; i < 4; ++i)
#pragma unroll
      for (int j = 0; j < NJ; ++j)
#pragma unroll
        for (int r2 = 0; r2 < 4; ++r2) {
          int row = m0 + wm + i * 16 + (fq << 2) + r2;
          int col = n0 + wn + j * 16 + fr;
          Cb[(size_t)row * ldc + col] += acc[i][j][r2];
        }
  } else {  // EPI_QK
    float* Cb = (float*)Cv + zq * cq + zr * cr;
    const float* Eb = extra + (size_t)bz * eq;
#pragma unroll
    for (int i = 0; i < 4; ++i)
#pragma unroll
      for (int j = 0; j < NJ; ++j)
#pragma unroll
        for (int r2 = 0; r2 < 4; ++r2) {
          int row = m0 + wm + i * 16 + (fq << 2) + r2;
          int col = n0 + wn + j * 16 + fr;
          Cb[(size_t)row * ldc + col] = acc[i][j][r2] * scale + Eb[(size_t)row * lde + col];
        }
  }
}

// Fused softmax(qk) @ V per (z, 64-row block). 256 thr (4 waves).
// Pass 1: exact row max + sum(exp) fully in registers (lane keeps its own
// row's m, 1/s via rr==fr). Pass 2: P computed on the fly into MFMA A-frags
// (qk re-read is L2/L3-warm), V staged in LDS (XOR-swizzled, double-buffered,
// counted vmcnt(8) — identical discipline to gemm128).
__global__ __launch_bounds__(256) void fsm_pv_kernel(const float* __restrict__ qko,
                                                     const u16* __restrict__ Vt,
                                                     u16* __restrict__ Am)
{
  __shared__ __align__(16) u16 Vbuf[2][16384];   // 2 x 32 KB: [256 d][64 k] bf16
  const int t = threadIdx.x;
  const int w = t >> 6, lane = t & 63;
  const int z = blockIdx.y, rb = blockIdx.x;
  const int fr = lane & 15, fq = lane >> 4;
  const float* Q = qko + (size_t)z * 1048576;     // [1024 rows][1024 t] f32
  const u16* Vz = Vt + (size_t)z * 262144;        // [256 d][1024 t] bf16
  const int r0w = rb * 64 + w * 16;               // wave's 16 rows

  auto STAGEV = [&](int kt, int sb) {
    const int k0 = kt << 6;
#pragma unroll
    for (int i8 = 0; i8 < 8; ++i8) {
      int cidx = (((i8 << 2) + w) << 6) + lane;   // chunk = d*8 + kc
      int d = cidx >> 3, kc = cidx & 7;
      GLDS(Vz + (size_t)d * 1024 + k0 + ((kc ^ (d & 7)) << 3),
           &Vbuf[sb][((i8 << 2) + w) << 9]);      // uniform base; HW adds lane*16B
    }
  };

  // prefetch V tiles 0,1 — latency hides under pass 1
  STAGEV(0, 0);
  STAGEV(1, 1);

  // pass 1: row max + sum of exp (wave-local rows; no LDS needed)
  float m_mine = 0.f, r_mine = 0.f;
#pragma unroll
  for (int rr = 0; rr < 16; ++rr) {
    const float* row = Q + (size_t)(r0w + rr) * 1024;
    f32x4 v[4];
#pragma unroll
    for (int i = 0; i < 4; ++i) v[i] = *(const f32x4*)&row[i * 256 + lane * 4];
    float m = v[0].x;
#pragma unroll
    for (int i = 0; i < 4; ++i)
      m = fmaxf(m, fmaxf(fmaxf(v[i].x, v[i].y), fmaxf(v[i].z, v[i].w)));
#pragma unroll
    for (int off = 32; off; off >>= 1) m = fmaxf(m, __shfl_xor(m, off));
    float s = 0.f;
#pragma unroll
    for (int i = 0; i < 4; ++i)
      s += __expf(v[i].x - m) + __expf(v[i].y - m) + __expf(v[i].z - m) + __expf(v[i].w - m);
#pragma unroll
    for (int off = 32; off; off >>= 1) s += __shfl_xor(s, off);
    if (rr == fr) { m_mine = m; r_mine = 1.f / s; }
  }

  f32x4 acc[16];
#pragma unroll
  for (int nf = 0; nf < 16; ++nf) acc[nf] = (f32x4){0.f, 0.f, 0.f, 0.f};

  const float* arow = Q + (size_t)(r0w + fr) * 1024 + fq * 8;

  for (int kt = 0; kt < 16; ++kt) {
    if (kt < 15) VMCNT_BAR(8); else VMCNT_BAR(0);
    const u16* Vb = &Vbuf[kt & 1][0];
#pragma unroll
    for (int ks = 0; ks < 2; ++ks) {
      f32x4 a0 = *(const f32x4*)&arow[kt * 64 + ks * 32 + 0];
      f32x4 a1 = *(const f32x4*)&arow[kt * 64 + ks * 32 + 4];
      union { u16x8 u; bfv8 b; } cvt;
      cvt.u[0] = f2bf(__expf(a0.x - m_mine) * r_mine);
      cvt.u[1] = f2bf(__expf(a0.y - m_mine) * r_mine);
      cvt.u[2] = f2bf(__expf(a0.z - m_mine) * r_mine);
      cvt.u[3] = f2bf(__expf(a0.w - m_mine) * r_mine);
      cvt.u[4] = f2bf(__expf(a1.x - m_mine) * r_mine);
      cvt.u[5] = f2bf(__expf(a1.y - m_mine) * r_mine);
      cvt.u[6] = f2bf(__expf(a1.z - m_mine) * r_mine);
      cvt.u[7] = f2bf(__expf(a1.w - m_mine) * r_mine);
      bfv8 av = cvt.b;
      __builtin_amdgcn_s_setprio(1);
#pragma unroll
      for (int nf = 0; nf < 16; ++nf) {
        int d = (nf << 4) + fr;
        int g = (ks << 2) + fq;
        bfv8 bv = *(const bfv8*)&Vb[(d << 6) + ((g ^ (d & 7)) << 3)];
        acc[nf] = __builtin_amdgcn_mfma_f32_16x16x32_bf16(av, bv, acc[nf], 0, 0, 0);
      }
      __builtin_amdgcn_s_setprio(0);
    }
    BAR_ONLY();
    if (kt + 2 < 16) STAGEV(kt + 2, kt & 1);
  }

  // write Am[b][row][n*256 + d] bf16
  const int b = z >> 2, n = z & 3;
  u16* Ao = Am + (size_t)b * 1048576 + n * 256;
#pragma unroll
  for (int nf = 0; nf < 16; ++nf)
#pragma unroll
    for (int r2 = 0; r2 < 4; ++r2) {
      int row = r0w + (fq << 2) + r2;
      Ao[(size_t)row * 1024 + (nf << 4) + fr] = f2bf(acc[nf][r2]);
    }
}

// Input projection via global_load_lds DMA staging.
__global__ __launch_bounds__(256) void proj4_kernel(const float* __restrict__ x,
                                                    const float* __restrict__ memp,
                                                    const float* __restrict__ ipw,
                                                    const float* __restrict__ ipb,
                                                    const float* __restrict__ mpw,
                                                    const float* __restrict__ mpb,
                                                    float* __restrict__ xs,
                                                    u16* __restrict__ msb)
{
  __shared__ __align__(16) float sbuf[2][16][256];   // 32 KB
  const int t = threadIdx.x;
  const int wid = t >> 6, lane = t & 63;
  const int task = blockIdx.z >> 2;
  const int b = blockIdx.z & 3;
  const int h0 = blockIdx.x << 4;
  const int w0 = blockIdx.y << 8;
  const float* src = task ? memp : x;
  const float* w8 = task ? mpw : ipw;
  const float bias = task ? mpb[0] : ipb[0];
  const int crot = (blockIdx.x + blockIdx.y + blockIdx.z) & 7;
  float wr[8];
#pragma unroll
  for (int j = 0; j < 8; ++j) wr[j] = w8[(j + crot) & 7];
  float acc[16];
#pragma unroll
  for (int h = 0; h < 16; ++h) acc[h] = bias;
  const size_t bbase = ((size_t)b * 8) << 20;

  auto STAGE_C = [&](int i, int sb) {
    const int c = (i + crot) & 7;
    const float* g = src + bbase + ((size_t)c << 20) + (size_t)h0 * 1024 + w0 + (lane << 2);
#pragma unroll
    for (int l = 0; l < 4; ++l) {
      int row = (wid << 2) + l;
      GLDS(g + (size_t)row * 1024, &sbuf[sb][row][0]);
    }
  };

  STAGE_C(0, 0);
  STAGE_C(1, 1);
#pragma unroll
  for (int i = 0; i < 8; ++i) {
    if (i < 7) VMCNT_BAR(4); else VMCNT_BAR(0);
    {
      const float wc = wr[i];
      const int sb = i & 1;
#pragma unroll
      for (int h = 0; h < 16; ++h)
        acc[h] += sbuf[sb][h][t] * wc;
    }
    BAR_ONLY();
    if (i + 2 < 8) STAGE_C(i + 2, i & 1);
  }

  if (task) {
    u16* d = &msb[((size_t)b * 1024 + w0 + t) * 1024 + h0];
    u16x8 o0, o1;
#pragma unroll
    for (int h = 0; h < 8; ++h) { o0[h] = f2bf(acc[h]); o1[h] = f2bf(acc[h + 8]); }
    *(u16x8*)&d[0] = o0;
    *(u16x8*)&d[8] = o1;
  } else {
    float* d = &xs[((size_t)b * 1024 + w0 + t) * 1024 + h0];
#pragma unroll
    for (int p = 0; p < 4; ++p) {
      f32x4 v = {acc[p * 4], acc[p * 4 + 1], acc[p * 4 + 2], acc[p * 4 + 3]};
      *(f32x4*)&d[p * 4] = v;
    }
  }
}

// LayerNorm over 1024, f32 in -> bf16 out. one block per row.
__global__ __launch_bounds__(256) void ln_kernel(const float* __restrict__ x,
                                                 const float* __restrict__ g,
                                                 const float* __restrict__ b,
                                                 u16* __restrict__ out)
{
  int row = blockIdx.x, tid = threadIdx.x;
  float4 v = ((const float4*)(x + (size_t)row * 1024))[tid];
  float s = v.x + v.y + v.z + v.w;
  float s2 = v.x * v.x + v.y * v.y + v.z * v.z + v.w * v.w;
#pragma unroll
  for (int o = 32; o; o >>= 1) { s += __shfl_down(s, o); s2 += __shfl_down(s2, o); }
  __shared__ float rs[4], rs2[4];
  int wid = tid >> 6, lane = tid & 63;
  if (lane == 0) { rs[wid] = s; rs2[wid] = s2; }
  __syncthreads();
  s = rs[0] + rs[1] + rs[2] + rs[3];
  s2 = rs2[0] + rs2[1] + rs2[2] + rs2[3];
  float mean = s * (1.f / 1024.f);
  float var = s2 * (1.f / 1024.f) - mean * mean;
  float rstd = rsqrtf(var + 1e-5f);
  float4 gv = ((const float4*)g)[tid];
  float4 bv = ((const float4*)b)[tid];
  ushort4 o;
  o.x = f2bf((v.x - mean) * rstd * gv.x + bv.x);
  o.y = f2bf((v.y - mean) * rstd * gv.y + bv.y);
  o.z = f2bf((v.z - mean) * rstd * gv.z + bv.z);
  o.w = f2bf((v.w - mean) * rstd * gv.w + bv.w);
  ((ushort4*)out)[(size_t)row * 256 + tid] = o;
}

// depthwise conv k=3 pad=1 along t for Q (sel=0) and K (sel=1) from fused QKV buffer.
__global__ __launch_bounds__(128) void dwconv_qk_kernel(const u16* __restrict__ qkv,
                                                        const float* __restrict__ qc,
                                                        const float* __restrict__ kc,
                                                        u16* __restrict__ Qc,
                                                        u16* __restrict__ Kc)
{
  int sel = blockIdx.y;
  int row = blockIdx.x;     // b*1024 + t
  int t = row & 1023;
  int c0 = threadIdx.x * 8;
  const u16* r0 = qkv + (size_t)row * 3072 + (sel << 10) + c0;
  const float* wc = sel ? kc : qc;
  u16* dst = (sel ? Kc : Qc) + (size_t)row * 1024 + c0;
  u16x8 zv = {0, 0, 0, 0, 0, 0, 0, 0};
  u16x8 xm = zv, xp = zv;
  if (t > 0) xm = *(const u16x8*)(r0 - 3072);
  u16x8 xc = *(const u16x8*)r0;
  if (t < 1023) xp = *(const u16x8*)(r0 + 3072);
  u16x8 o;
#pragma unroll
  for (int j = 0; j < 8; ++j) {
    int c = c0 + j;
    float v = bf2f(xm[j]) * wc[c * 3 + 0] + bf2f(xc[j]) * wc[c * 3 + 1] + bf2f(xp[j]) * wc[c * 3 + 2];
    o[j] = f2bf(v);
  }
  *(u16x8*)dst = o;
}

// depthwise conv + transposed store for V: out[(b*4+c/256)][c%256][t] from qkv col 2048+c
__global__ __launch_bounds__(1024) void dwconv_t_kernel(const u16* __restrict__ qkv,
                                                        const float* __restrict__ wc,
                                                        u16* __restrict__ out)
{
  __shared__ float tile[32][33];
  int b = blockIdx.z;
  int t = blockIdx.x * 32 + threadIdx.y;
  int c = blockIdx.y * 32 + threadIdx.x;
  size_t base = ((size_t)b * 1024 + t) * 3072 + 2048 + c;
  float xm = (t > 0) ? bf2f(qkv[base - 3072]) : 0.f;
  float xc = bf2f(qkv[base]);
  float xp = (t < 1023) ? bf2f(qkv[base + 3072]) : 0.f;
  tile[threadIdx.y][threadIdx.x] = xm * wc[c * 3 + 0] + xc * wc[c * 3 + 1] + xp * wc[c * 3 + 2];
  __syncthreads();
  int c2 = blockIdx.y * 32 + threadIdx.y;
  int t2 = blockIdx.x * 32 + threadIdx.x;
  int z = b * 4 + (c2 >> 8);
  out[((size_t)z * 256 + (c2 & 255)) * 1024 + t2] = f2bf(tile[threadIdx.x][threadIdx.y]);
}

// 12 fused f32->bf16 casts of 1M elements each (weight prep, one launch)
struct CastJobs { const float* s[12]; u16* d[12]; };
__global__ __launch_bounds__(256) void cast12_kernel(CastJobs J)
{
  int j = blockIdx.y;
  int i = blockIdx.x * 256 + threadIdx.x;   // 262144 float4 per job
  float4 v = ((const float4*)J.s[j])[i];
  ushort4 o;
  o.x = f2bf(v.x); o.y = f2bf(v.y); o.z = f2bf(v.z); o.w = f2bf(v.w);
  ((ushort4*)J.d[j])[i] = o;
}

// pw [256][1024] f32 -> pwT [1024][256] bf16
__global__ __launch_bounds__(1024) void pwt_kernel(const float* __restrict__ pw,
                                                   u16* __restrict__ pwT)
{
  __shared__ float tile[32][33];
  int d = blockIdx.y * 32 + threadIdx.y;
  int t = blockIdx.x * 32 + threadIdx.x;
  tile[threadIdx.y][threadIdx.x] = pw[(size_t)d * 1024 + t];
  __syncthreads();
  int t2 = blockIdx.x * 32 + threadIdx.y;
  int d2 = blockIdx.y * 32 + threadIdx.x;
  pwT[(size_t)t2 * 256 + d2] = f2bf(tile[threadIdx.x][threadIdx.y]);
}

// out[b][h][w] = xs[b][w][h], f32
__global__ __launch_bounds__(1024) void tout_kernel(const float* __restrict__ xs,
                                                    float* __restrict__ out)
{
  __shared__ float tile[32][33];
  int b = blockIdx.z;
  int w = blockIdx.x * 32 + threadIdx.y;
  int h = blockIdx.y * 32 + threadIdx.x;
  tile[threadIdx.y][threadIdx.x] = xs[((size_t)b * 1024 + w) * 1024 + h];
  __syncthreads();
  int h2 = blockIdx.y * 32 + threadIdx.y;
  int w2 = blockIdx.x * 32 + threadIdx.x;
  out[((size_t)b * 1024 + h2) * 1024 + w2] = tile[threadIdx.x][threadIdx.y];
}

static void run_attn(hipStream_t stream, float* xs, const u16* qsrc, const u16* kvsrc, int asplit,
                     u16* QKVraw, u16* Qc, u16* Kc, u16* Vt, u16* Am,
                     const u16* wqkv, const u16* wo, const u16* pwt,
                     const float* qc, const float* kc, const float* vc,
                     const float* prevqk, float* qko)
{
  dim3 blk(512);
  // fused QKV projection: M=4096, N=3072, K=1024. 768 blocks.
  gemm128<EPI_BF16, false><<<dim3(24, 32, 1), blk, 0, stream>>>(
      qsrc, kvsrc, asplit, 0, 0, 1024, nullptr, 0,
      wqkv, 0, 0, 1024, nullptr, 0, 0, 0,
      1024, 0, QKVraw, 0, 0, 3072, nullptr, 0, 0, 1.f);
  dwconv_qk_kernel<<<dim3(4096, 2), 128, 0, stream>>>(QKVraw, qc, kc, Qc, Kc);
  dwconv_t_kernel<<<dim3(32, 32, 4), dim3(32, 32), 0, stream>>>(QKVraw, vc, Vt);
  // qk = (Q Kt + pwT Qt)/32 + prev, K=512 split at 256. 1024 blocks.
  gemm128<EPI_QK, true><<<dim3(8, 8, 16), blk, 0, stream>>>(
      Qc, Qc, 1 << 30, 1048576, 256, 1024, pwt, 256,
      Kc, 1048576, 256, 1024, Qc, 1048576, 256, 1024,
      512, 256, qko, 4194304, 1048576, 1024, prevqk, 1048576, 1024, 0.03125f);
  // fused softmax + PV: 256 blocks (16 row-blocks x 16 z)
  fsm_pv_kernel<<<dim3(16, 16), 256, 0, stream>>>(qko, Vt, Am);
  // O-proj + residual add into xs (f32). 256 blocks.
  gemm128<EPI_ADDF32, false><<<dim3(8, 32, 1), blk, 0, stream>>>(
      Am, Am, 1 << 30, 0, 0, 1024, nullptr, 0,
      wo, 0, 0, 1024, nullptr, 0, 0, 0,
      1024, 0, xs, 0, 0, 1024, nullptr, 0, 0, 1.f);
}

extern "C" void kernel_launch(void* const* d_in, const int* in_sizes, int n_in,
                              void* d_out, int out_size, void* d_ws, size_t ws_size,
                              hipStream_t stream)
{
  (void)in_sizes; (void)n_in; (void)out_size; (void)ws_size;
  const float* x    = (const float*)d_in[0];
  const float* memp = (const float*)d_in[1];
  const float* pqk1 = (const float*)d_in[2];
  const float* pqk2 = (const float*)d_in[3];
  const float* ip_w = (const float*)d_in[4];
  const float* ip_b = (const float*)d_in[5];
  const float* mp_w = (const float*)d_in[6];
  const float* mp_b = (const float*)d_in[7];
  const float* ln1g = (const float*)d_in[8];
  const float* ln1b = (const float*)d_in[9];
  const float* ln2g = (const float*)d_in[10];
  const float* ln2b = (const float*)d_in[11];
  const float* ln3g = (const float*)d_in[12];
  const float* ln3b = (const float*)d_in[13];
  const float* a1qw = (const float*)d_in[14];
  const float* a1qc = (const float*)d_in[15];
  const float* a1kw = (const float*)d_in[16];
  const float* a1kc = (const float*)d_in[17];
  const float* a1vw = (const float*)d_in[18];
  const float* a1vc = (const float*)d_in[19];
  const float* a1ow = (const float*)d_in[20];
  const float* a1pw = (const float*)d_in[21];
  const float* a2qw = (const float*)d_in[22];
  const float* a2qc = (const float*)d_in[23];
  const float* a2kw = (const float*)d_in[24];
  const float* a2kc = (const float*)d_in[25];
  const float* a2vw = (const float*)d_in[26];
  const float* a2vc = (const float*)d_in[27];
  const float* a2ow = (const float*)d_in[28];
  const float* a2pw = (const float*)d_in[29];
  const float* l1w  = (const float*)d_in[30];
  const float* l2w  = (const float*)d_in[31];

  float* outp = (float*)d_out;
  float* qk1o = outp + 4194304;    // [4][4][1024][1024]
  float* qk2o = outp + 20971520;

  const size_t MB = 1024 * 1024;
  char* W = (char*)d_ws;
  float* xs   = (float*)(W);             // 16MB f32 [4][1024w][1024h]
  u16* msb    = (u16*)(W + 16 * MB);     // 8MB bf16
  u16* xln    = (u16*)(W + 24 * MB);     // 8MB
  u16* QKVraw = (u16*)(W + 32 * MB);     // 24MB [4096][3072]
  u16* Qc     = (u16*)(W + 56 * MB);     // 8MB
  u16* Kc     = (u16*)(W + 64 * MB);     // 8MB
  u16* Vt     = (u16*)(W + 72 * MB);     // 8MB  [16][256][1024]
  u16* Am     = (u16*)(W + 112 * MB);    // 8MB
  u16* wqkv1  = (u16*)(W + 120 * MB);    // 6MB [3072][1024]
  u16* wqkv2  = (u16*)(W + 126 * MB);    // 6MB
  u16* wo1    = (u16*)(W + 132 * MB);    // 2MB
  u16* wo2    = (u16*)(W + 134 * MB);    // 2MB
  u16* wl1    = (u16*)(W + 136 * MB);    // 4MB [2048][1024]
  u16* wl2    = (u16*)(W + 140 * MB);    // 4MB [1024][2048]
  u16* pwt1   = (u16*)(W + 144 * MB);    // 0.5MB [1024][256]
  u16* pwt2   = (u16*)(W + 144 * MB + 512 * 1024);
  u16* H1     = QKVraw;                  // 16MB overlay (dead in FFN)

  CastJobs J;
  J.s[0] = a1qw; J.d[0] = wqkv1;
  J.s[1] = a1kw; J.d[1] = wqkv1 + 1048576;
  J.s[2] = a1vw; J.d[2] = wqkv1 + 2097152;
  J.s[3] = a2qw; J.d[3] = wqkv2;
  J.s[4] = a2kw; J.d[4] = wqkv2 + 1048576;
  J.s[5] = a2vw; J.d[5] = wqkv2 + 2097152;
  J.s[6] = a1ow; J.d[6] = wo1;
  J.s[7] = a2ow; J.d[7] = wo2;
  J.s[8] = l1w;            J.d[8] = wl1;
  J.s[9] = l1w + 1048576;  J.d[9] = wl1 + 1048576;
  J.s[10] = l2w;           J.d[10] = wl2;
  J.s[11] = l2w + 1048576; J.d[11] = wl2 + 1048576;
  cast12_kernel<<<dim3(1024, 12), 256, 0, stream>>>(J);
  pwt_kernel<<<dim3(32, 8, 1), dim3(32, 32), 0, stream>>>(a1pw, pwt1);
  pwt_kernel<<<dim3(32, 8, 1), dim3(32, 32), 0, stream>>>(a2pw, pwt2);

  // input projections: DMA-staged (global_load_lds) read path
  proj4_kernel<<<dim3(64, 4, 8), 256, 0, stream>>>(
      x, memp, ip_w, ip_b, mp_w, mp_b, xs, msb);

  // attention 1 (self): q and kv both from LN1(xs)
  ln_kernel<<<4096, 256, 0, stream>>>(xs, ln1g, ln1b, xln);
  run_attn(stream, xs, xln, xln, 1 << 30, QKVraw, Qc, Kc, Vt, Am,
           wqkv1, wo1, pwt1, a1qc, a1kc, a1vc, pqk1, qk1o);

  // attention 2 (cross): q from LN2(xs), kv from ms
  ln_kernel<<<4096, 256, 0, stream>>>(xs, ln2g, ln2b, xln);
  run_attn(stream, xs, xln, msb, 1024, QKVraw, Qc, Kc, Vt, Am,
           wqkv2, wo2, pwt2, a2qc, a2kc, a2vc, pqk2, qk2o);

  // FFN
  ln_kernel<<<4096, 256, 0, stream>>>(xs, ln3g, ln3b, xln);
  gemm128<EPI_RELU2, false><<<dim3(16, 32, 1), dim3(512), 0, stream>>>(
      xln, xln, 1 << 30, 0, 0, 1024, nullptr, 0,
      wl1, 0, 0, 1024, nullptr, 0, 0, 0,
      1024, 0, H1, 0, 0, 2048, nullptr, 0, 0, 1.f);
  gemm128<EPI_ADDF32, false><<<dim3(8, 32, 1), dim3(512), 0, stream>>>(
      H1, H1, 1 << 30, 0, 0, 2048, nullptr, 0,
      wl2, 0, 0, 2048, nullptr, 0, 0, 0,
      2048, 0, xs, 0, 0, 1024, nullptr, 0, 0, 1.f);

  // final transpose to out[b][1][bins][w]
  tout_kernel<<<dim3(32, 32, 4), dim3(32, 32), 0, stream>>>(xs, outp);
}

// Round 10
// 483.921 us; speedup vs baseline: 1.0251x; 1.0251x over previous
//
#include <hip/hip_runtime.h>
#include <stdint.h>

typedef unsigned short u16;
typedef __bf16 bfv8 __attribute__((ext_vector_type(8)));
typedef float f32x4 __attribute__((ext_vector_type(4)));
typedef unsigned short u16x8 __attribute__((ext_vector_type(8)));

#define DI __device__ __forceinline__

DI u16 f2bf(float f) {
  union { float f; unsigned u; } c; c.f = f;
  unsigned r = c.u + 0x7FFFu + ((c.u >> 16) & 1u);
  return (u16)(r >> 16);
}
DI float bf2f(u16 b) {
  union { unsigned u; float f; } c; c.u = ((unsigned)b) << 16;
  return c.f;
}

enum { EPI_BF16 = 0, EPI_RELU2 = 1, EPI_ADDF32 = 2, EPI_QK = 3 };

#define GLDS(g, l)                                                              \
  __builtin_amdgcn_global_load_lds((const __attribute__((address_space(1))) void*)(g), \
                                   (__attribute__((address_space(3))) void*)(l), 16, 0, 0)

#define VMCNT_BAR(N)                                        \
  do {                                                      \
    asm volatile("s_waitcnt vmcnt(" #N ")" ::: "memory");   \
    __builtin_amdgcn_sched_barrier(0);                      \
    __builtin_amdgcn_s_barrier();                           \
    __builtin_amdgcn_sched_barrier(0);                      \
  } while (0)

#define BAR_ONLY()                                          \
  do {                                                      \
    __builtin_amdgcn_sched_barrier(0);                      \
    __builtin_amdgcn_s_barrier();                           \
    __builtin_amdgcn_sched_barrier(0);                      \
  } while (0)

// C[m,n] = sum_k A[m,k]*B[n,k]. Tile 128xBN, BK=64.
// BN=128: 512 thr (8 waves), LDS 64KB dbuf -> 2 blocks/CU.
// BN=64:  256 thr (4 waves), LDS 48KB dbuf -> 3 blocks/CU (for small-N GEMMs).
// 2-stage double-buffer, counted vmcnt (LPS in flight), setprio.
// Bijective chunked XCD swizzle (m204). LDS XOR swizzle round-1-verified.
template <int EPI, bool KSPLIT, int BN>
__global__ __launch_bounds__(BN == 128 ? 512 : 256, BN == 128 ? 4 : 3) void gemm_t(
    const u16* __restrict__ Aq, const u16* __restrict__ Akv, int asplit,
    long a1q, long a1r, int lda1,
    const u16* __restrict__ A2, int lda2,
    const u16* __restrict__ B1, long b1q, long b1r, int ldb1,
    const u16* __restrict__ B2, long b2q, long b2r, int ldb2,
    int K, int ksp,
    void* __restrict__ Cv, long cq, long cr, int ldc,
    const float* __restrict__ extra, long eq, int lde,
    float scale)
{
  constexpr int NTHR = (BN == 128) ? 512 : 256;
  constexpr int NW = NTHR / 64;          // waves per block
  constexpr int ALO = 1024 / NTHR;       // A staging loads per thread (2 or 4)
  constexpr int SS = 8192 + BN * 64;     // u16 per stage
  __shared__ __align__(16) u16 lds[2 * SS];
  const int tid = threadIdx.x;
  const int wid = tid >> 6, lane = tid & 63;

  const int gx = gridDim.x, gy = gridDim.y;
  const int nwg = gx * gy * (int)gridDim.z;
  const int flat = blockIdx.x + gx * (blockIdx.y + gy * blockIdx.z);
  const int q = nwg >> 3, r = nwg & 7;
  const int xcd = flat & 7, idx = flat >> 3;
  const int wg = (xcd < r ? xcd * (q + 1) : r * (q + 1) + (xcd - r) * q) + idx;
  const int bx = wg % gx;
  const int tmp = wg / gx;
  const int by = tmp % gy;
  const int bz = tmp / gy;

  const long zq = bz >> 2, zr = bz & 3;
  const int m0 = by * 128, n0 = bx * BN;
  const u16* Ab = ((n0 >= asplit) ? Akv : Aq) + zq * a1q + zr * a1r;
  const u16* Bb = B1 + zq * b1q + zr * b1r;
  const u16* B2b = KSPLIT ? (B2 + zq * b2q + zr * b2r) : (const u16*)nullptr;
  const int wm = (wid / (NW / 2)) * 64, wn = (wid % (NW / 2)) * 32;
  const int fr = lane & 15, fq = lane >> 4;

  f32x4 acc[4][2];
#pragma unroll
  for (int i = 0; i < 4; ++i)
#pragma unroll
    for (int j = 0; j < 2; ++j)
      acc[i][j] = (f32x4){0.f, 0.f, 0.f, 0.f};

  const int nt = K >> 6;

  auto STAGE = [&](int tt, int sb) {
    const int k0 = tt << 6;
    u16* Ld = &lds[sb * SS];
    const u16* Asrc; int la; const u16* Bsrc; int lb;
    if (!KSPLIT || k0 < ksp) { Asrc = Ab + k0; la = lda1; Bsrc = Bb + k0; lb = ldb1; }
    else { Asrc = A2 + (k0 - ksp); la = lda2; Bsrc = B2b + (k0 - ksp); lb = ldb2; }
#pragma unroll
    for (int l = 0; l < ALO; ++l) {             // A: 1024 chunks
      int idx2 = l * NTHR + tid;
      int row = idx2 >> 3;
      int sc = ((idx2 & 7) ^ (row & 7)) << 3;   // pre-swizzled global column
      GLDS(Asrc + (size_t)(m0 + row) * la + sc,
           Ld + ((l * NW + wid) << 9));
    }
#pragma unroll
    for (int l = 0; l < 2; ++l) {               // B: BN*8 chunks / NTHR = 2 loads
      int idx2 = l * NTHR + tid;
      int row = idx2 >> 3;
      int sc = ((idx2 & 7) ^ (row & 7)) << 3;
      GLDS(Bsrc + (size_t)(n0 + row) * lb + sc,
           Ld + 8192 + ((l * NW + wid) << 9));
    }
  };

  auto COMPUTE = [&](int cb) {
    const u16* As = &lds[cb * SS];
    const u16* Bs = As + 8192;
#pragma unroll
    for (int ks = 0; ks < 2; ++ks) {
      bfv8 av[4];
#pragma unroll
      for (int i = 0; i < 4; ++i) {
        int ra = wm + i * 16 + fr;
        int ca = (((ks << 2) + fq) ^ (ra & 7)) << 3;
        av[i] = *(const bfv8*)&As[(ra << 6) + ca];
      }
      bfv8 bv[2];
#pragma unroll
      for (int j = 0; j < 2; ++j) {
        int rb = wn + (j << 4) + fr;
        int cb2 = (((ks << 2) + fq) ^ (rb & 7)) << 3;
        bv[j] = *(const bfv8*)&Bs[(rb << 6) + cb2];
      }
      __builtin_amdgcn_s_setprio(1);
#pragma unroll
      for (int i = 0; i < 4; ++i) {
        acc[i][0] = __builtin_amdgcn_mfma_f32_16x16x32_bf16(av[i], bv[0], acc[i][0], 0, 0, 0);
        acc[i][1] = __builtin_amdgcn_mfma_f32_16x16x32_bf16(av[i], bv[1], acc[i][1], 0, 0, 0);
      }
      __builtin_amdgcn_s_setprio(0);
    }
  };

  STAGE(0, 0);
  STAGE(1, 1);
  if constexpr (BN == 128) VMCNT_BAR(4); else VMCNT_BAR(6);
  for (int t = 0; t < nt; ++t) {
    COMPUTE(t & 1);
    BAR_ONLY();
    if (t + 2 < nt) {
      STAGE(t + 2, t & 1);
      if constexpr (BN == 128) VMCNT_BAR(4); else VMCNT_BAR(6);
    } else if (t + 1 < nt) {
      VMCNT_BAR(0);
    }
  }

  if constexpr (EPI == EPI_BF16 || EPI == EPI_RELU2) {
    u16* Cb = (u16*)Cv + zq * cq + zr * cr;
#pragma unroll
    for (int i = 0; i < 4; ++i)
#pragma unroll
      for (int j = 0; j < 2; ++j)
#pragma unroll
        for (int r2 = 0; r2 < 4; ++r2) {
          int row = m0 + wm + i * 16 + (fq << 2) + r2;
          int col = n0 + wn + j * 16 + fr;
          float v = acc[i][j][r2];
          if constexpr (EPI == EPI_RELU2) { v = fmaxf(v, 0.f); v = v * v; }
          Cb[(size_t)row * ldc + col] = f2bf(v);
        }
  } else if constexpr (EPI == EPI_ADDF32) {
    float* Cb = (float*)Cv + zq * cq + zr * cr;
#pragma unroll
    for (int i = 0; i < 4; ++i)
#pragma unroll
      for (int j = 0; j < 2; ++j)
#pragma unroll
        for (int r2 = 0; r2 < 4; ++r2) {
          int row = m0 + wm + i * 16 + (fq << 2) + r2;
          int col = n0 + wn + j * 16 + fr;
          Cb[(size_t)row * ldc + col] += acc[i][j][r2];
        }
  } else {  // EPI_QK
    float* Cb = (float*)Cv + zq * cq + zr * cr;
    const float* Eb = extra + (size_t)bz * eq;
#pragma unroll
    for (int i = 0; i < 4; ++i)
#pragma unroll
      for (int j = 0; j < 2; ++j)
#pragma unroll
        for (int r2 = 0; r2 < 4; ++r2) {
          int row = m0 + wm + i * 16 + (fq << 2) + r2;
          int col = n0 + wn + j * 16 + fr;
          Cb[(size_t)row * ldc + col] = acc[i][j][r2] * scale + Eb[(size_t)row * lde + col];
        }
  }
}

// Input projection via global_load_lds DMA staging.
__global__ __launch_bounds__(256) void proj4_kernel(const float* __restrict__ x,
                                                    const float* __restrict__ memp,
                                                    const float* __restrict__ ipw,
                                                    const float* __restrict__ ipb,
                                                    const float* __restrict__ mpw,
                                                    const float* __restrict__ mpb,
                                                    float* __restrict__ xs,
                                                    u16* __restrict__ msb)
{
  __shared__ __align__(16) float sbuf[2][16][256];   // 32 KB
  const int t = threadIdx.x;
  const int wid = t >> 6, lane = t & 63;
  const int task = blockIdx.z >> 2;
  const int b = blockIdx.z & 3;
  const int h0 = blockIdx.x << 4;
  const int w0 = blockIdx.y << 8;
  const float* src = task ? memp : x;
  const float* w8 = task ? mpw : ipw;
  const float bias = task ? mpb[0] : ipb[0];
  const int crot = (blockIdx.x + blockIdx.y + blockIdx.z) & 7;
  float wr[8];
#pragma unroll
  for (int j = 0; j < 8; ++j) wr[j] = w8[(j + crot) & 7];
  float acc[16];
#pragma unroll
  for (int h = 0; h < 16; ++h) acc[h] = bias;
  const size_t bbase = ((size_t)b * 8) << 20;

  auto STAGE_C = [&](int i, int sb) {
    const int c = (i + crot) & 7;
    const float* g = src + bbase + ((size_t)c << 20) + (size_t)h0 * 1024 + w0 + (lane << 2);
#pragma unroll
    for (int l = 0; l < 4; ++l) {
      int row = (wid << 2) + l;
      GLDS(g + (size_t)row * 1024, &sbuf[sb][row][0]);
    }
  };

  STAGE_C(0, 0);
  STAGE_C(1, 1);
#pragma unroll
  for (int i = 0; i < 8; ++i) {
    if (i < 7) VMCNT_BAR(4); else VMCNT_BAR(0);
    {
      const float wc = wr[i];
      const int sb = i & 1;
#pragma unroll
      for (int h = 0; h < 16; ++h)
        acc[h] += sbuf[sb][h][t] * wc;
    }
    BAR_ONLY();
    if (i + 2 < 8) STAGE_C(i + 2, i & 1);
  }

  if (task) {
    u16* d = &msb[((size_t)b * 1024 + w0 + t) * 1024 + h0];
    u16x8 o0, o1;
#pragma unroll
    for (int h = 0; h < 8; ++h) { o0[h] = f2bf(acc[h]); o1[h] = f2bf(acc[h + 8]); }
    *(u16x8*)&d[0] = o0;
    *(u16x8*)&d[8] = o1;
  } else {
    float* d = &xs[((size_t)b * 1024 + w0 + t) * 1024 + h0];
#pragma unroll
    for (int p = 0; p < 4; ++p) {
      f32x4 v = {acc[p * 4], acc[p * 4 + 1], acc[p * 4 + 2], acc[p * 4 + 3]};
      *(f32x4*)&d[p * 4] = v;
    }
  }
}

// LayerNorm over 1024, f32 in -> bf16 out. one block per row.
__global__ __launch_bounds__(256) void ln_kernel(const float* __restrict__ x,
                                                 const float* __restrict__ g,
                                                 const float* __restrict__ b,
                                                 u16* __restrict__ out)
{
  int row = blockIdx.x, tid = threadIdx.x;
  float4 v = ((const float4*)(x + (size_t)row * 1024))[tid];
  float s = v.x + v.y + v.z + v.w;
  float s2 = v.x * v.x + v.y * v.y + v.z * v.z + v.w * v.w;
#pragma unroll
  for (int o = 32; o; o >>= 1) { s += __shfl_down(s, o); s2 += __shfl_down(s2, o); }
  __shared__ float rs[4], rs2[4];
  int wid = tid >> 6, lane = tid & 63;
  if (lane == 0) { rs[wid] = s; rs2[wid] = s2; }
  __syncthreads();
  s = rs[0] + rs[1] + rs[2] + rs[3];
  s2 = rs2[0] + rs2[1] + rs2[2] + rs2[3];
  float mean = s * (1.f / 1024.f);
  float var = s2 * (1.f / 1024.f) - mean * mean;
  float rstd = rsqrtf(var + 1e-5f);
  float4 gv = ((const float4*)g)[tid];
  float4 bv = ((const float4*)b)[tid];
  ushort4 o;
  o.x = f2bf((v.x - mean) * rstd * gv.x + bv.x);
  o.y = f2bf((v.y - mean) * rstd * gv.y + bv.y);
  o.z = f2bf((v.z - mean) * rstd * gv.z + bv.z);
  o.w = f2bf((v.w - mean) * rstd * gv.w + bv.w);
  ((ushort4*)out)[(size_t)row * 256 + tid] = o;
}

// depthwise conv k=3 pad=1 along t for Q (sel=0) and K (sel=1) from fused QKV buffer.
__global__ __launch_bounds__(128) void dwconv_qk_kernel(const u16* __restrict__ qkv,
                                                        const float* __restrict__ qc,
                                                        const float* __restrict__ kc,
                                                        u16* __restrict__ Qc,
                                                        u16* __restrict__ Kc)
{
  int sel = blockIdx.y;
  int row = blockIdx.x;     // b*1024 + t
  int t = row & 1023;
  int c0 = threadIdx.x * 8;
  const u16* r0 = qkv + (size_t)row * 3072 + (sel << 10) + c0;
  const float* wc = sel ? kc : qc;
  u16* dst = (sel ? Kc : Qc) + (size_t)row * 1024 + c0;
  u16x8 zv = {0, 0, 0, 0, 0, 0, 0, 0};
  u16x8 xm = zv, xp = zv;
  if (t > 0) xm = *(const u16x8*)(r0 - 3072);
  u16x8 xc = *(const u16x8*)r0;
  if (t < 1023) xp = *(const u16x8*)(r0 + 3072);
  u16x8 o;
#pragma unroll
  for (int j = 0; j < 8; ++j) {
    int c = c0 + j;
    float v = bf2f(xm[j]) * wc[c * 3 + 0] + bf2f(xc[j]) * wc[c * 3 + 1] + bf2f(xp[j]) * wc[c * 3 + 2];
    o[j] = f2bf(v);
  }
  *(u16x8*)dst = o;
}

// depthwise conv + transposed store for V: out[(b*4+c/256)][c%256][t] from qkv col 2048+c
__global__ __launch_bounds__(1024) void dwconv_t_kernel(const u16* __restrict__ qkv,
                                                        const float* __restrict__ wc,
                                                        u16* __restrict__ out)
{
  __shared__ float tile[32][33];
  int b = blockIdx.z;
  int t = blockIdx.x * 32 + threadIdx.y;
  int c = blockIdx.y * 32 + threadIdx.x;
  size_t base = ((size_t)b * 1024 + t) * 3072 + 2048 + c;
  float xm = (t > 0) ? bf2f(qkv[base - 3072]) : 0.f;
  float xc = bf2f(qkv[base]);
  float xp = (t < 1023) ? bf2f(qkv[base + 3072]) : 0.f;
  tile[threadIdx.y][threadIdx.x] = xm * wc[c * 3 + 0] + xc * wc[c * 3 + 1] + xp * wc[c * 3 + 2];
  __syncthreads();
  int c2 = blockIdx.y * 32 + threadIdx.y;
  int t2 = blockIdx.x * 32 + threadIdx.x;
  int z = b * 4 + (c2 >> 8);
  out[((size_t)z * 256 + (c2 & 255)) * 1024 + t2] = f2bf(tile[threadIdx.x][threadIdx.y]);
}

// row softmax over 1024, f32 in -> bf16 out
__global__ __launch_bounds__(256) void softmax_kernel(const float* __restrict__ qk,
                                                      u16* __restrict__ P)
{
  size_t row = blockIdx.x;
  int tid = threadIdx.x;
  float4 v = ((const float4*)(qk + row * 1024))[tid];
  float m = fmaxf(fmaxf(v.x, v.y), fmaxf(v.z, v.w));
#pragma unroll
  for (int o = 32; o; o >>= 1) m = fmaxf(m, __shfl_down(m, o));
  __shared__ float red[4];
  int wid = tid >> 6, lane = tid & 63;
  if (lane == 0) red[wid] = m;
  __syncthreads();
  m = fmaxf(fmaxf(red[0], red[1]), fmaxf(red[2], red[3]));
  float e0 = __expf(v.x - m), e1 = __expf(v.y - m), e2 = __expf(v.z - m), e3 = __expf(v.w - m);
  float s = e0 + e1 + e2 + e3;
#pragma unroll
  for (int o = 32; o; o >>= 1) s += __shfl_down(s, o);
  __syncthreads();
  if (lane == 0) red[wid] = s;
  __syncthreads();
  s = red[0] + red[1] + red[2] + red[3];
  float rinv = 1.f / s;
  ushort4 o;
  o.x = f2bf(e0 * rinv); o.y = f2bf(e1 * rinv); o.z = f2bf(e2 * rinv); o.w = f2bf(e3 * rinv);
  ((ushort4*)P)[row * 256 + tid] = o;
}

// 12 fused f32->bf16 casts of 1M elements each (weight prep, one launch)
struct CastJobs { const float* s[12]; u16* d[12]; };
__global__ __launch_bounds__(256) void cast12_kernel(CastJobs J)
{
  int j = blockIdx.y;
  int i = blockIdx.x * 256 + threadIdx.x;   // 262144 float4 per job
  float4 v = ((const float4*)J.s[j])[i];
  ushort4 o;
  o.x = f2bf(v.x); o.y = f2bf(v.y); o.z = f2bf(v.z); o.w = f2bf(v.w);
  ((ushort4*)J.d[j])[i] = o;
}

// pw [256][1024] f32 -> pwT [1024][256] bf16
__global__ __launch_bounds__(1024) void pwt_kernel(const float* __restrict__ pw,
                                                   u16* __restrict__ pwT)
{
  __shared__ float tile[32][33];
  int d = blockIdx.y * 32 + threadIdx.y;
  int t = blockIdx.x * 32 + threadIdx.x;
  tile[threadIdx.y][threadIdx.x] = pw[(size_t)d * 1024 + t];
  __syncthreads();
  int t2 = blockIdx.x * 32 + threadIdx.y;
  int d2 = blockIdx.y * 32 + threadIdx.x;
  pwT[(size_t)t2 * 256 + d2] = f2bf(tile[threadIdx.x][threadIdx.y]);
}

// out[b][h][w] = xs[b][w][h], f32
__global__ __launch_bounds__(1024) void tout_kernel(const float* __restrict__ xs,
                                                    float* __restrict__ out)
{
  __shared__ float tile[32][33];
  int b = blockIdx.z;
  int w = blockIdx.x * 32 + threadIdx.y;
  int h = blockIdx.y * 32 + threadIdx.x;
  tile[threadIdx.y][threadIdx.x] = xs[((size_t)b * 1024 + w) * 1024 + h];
  __syncthreads();
  int h2 = blockIdx.y * 32 + threadIdx.y;
  int w2 = blockIdx.x * 32 + threadIdx.x;
  out[((size_t)b * 1024 + h2) * 1024 + w2] = tile[threadIdx.x][threadIdx.y];
}

static void run_attn(hipStream_t stream, float* xs, const u16* qsrc, const u16* kvsrc, int asplit,
                     u16* QKVraw, u16* Qc, u16* Kc, u16* Vt, u16* P, u16* Am,
                     const u16* wqkv, const u16* wo, const u16* pwt,
                     const float* qc, const float* kc, const float* vc,
                     const float* prevqk, float* qko)
{
  // fused QKV projection: M=4096, N=3072, K=1024. 768 blocks @ 2/CU.
  gemm_t<EPI_BF16, false, 128><<<dim3(24, 32, 1), dim3(512), 0, stream>>>(
      qsrc, kvsrc, asplit, 0, 0, 1024, nullptr, 0,
      wqkv, 0, 0, 1024, nullptr, 0, 0, 0,
      1024, 0, QKVraw, 0, 0, 3072, nullptr, 0, 0, 1.f);
  dwconv_qk_kernel<<<dim3(4096, 2), 128, 0, stream>>>(QKVraw, qc, kc, Qc, Kc);
  dwconv_t_kernel<<<dim3(32, 32, 4), dim3(32, 32), 0, stream>>>(QKVraw, vc, Vt);
  // qk = (Q Kt + pwT Qt)/32 + prev, K=512 split at 256. 1024 blocks.
  gemm_t<EPI_QK, true, 128><<<dim3(8, 8, 16), dim3(512), 0, stream>>>(
      Qc, Qc, 1 << 30, 1048576, 256, 1024, pwt, 256,
      Kc, 1048576, 256, 1024, Qc, 1048576, 256, 1024,
      512, 256, qko, 4194304, 1048576, 1024, prevqk, 1048576, 1024, 0.03125f);
  softmax_kernel<<<16384, 256, 0, stream>>>(qko, P);
  // PV: per z, [1024x1024]x[1024x256]. BN=64 -> 512 blocks @ 3/CU.
  gemm_t<EPI_BF16, false, 64><<<dim3(4, 8, 16), dim3(256), 0, stream>>>(
      P, P, 1 << 30, 4194304, 1048576, 1024, nullptr, 0,
      Vt, 1048576, 262144, 1024, nullptr, 0, 0, 0,
      1024, 0, Am, 1048576, 256, 1024, nullptr, 0, 0, 1.f);
  // O-proj + residual add into xs (f32). BN=64 -> 512 blocks.
  gemm_t<EPI_ADDF32, false, 64><<<dim3(16, 32, 1), dim3(256), 0, stream>>>(
      Am, Am, 1 << 30, 0, 0, 1024, nullptr, 0,
      wo, 0, 0, 1024, nullptr, 0, 0, 0,
      1024, 0, xs, 0, 0, 1024, nullptr, 0, 0, 1.f);
}

extern "C" void kernel_launch(void* const* d_in, const int* in_sizes, int n_in,
                              void* d_out, int out_size, void* d_ws, size_t ws_size,
                              hipStream_t stream)
{
  (void)in_sizes; (void)n_in; (void)out_size; (void)ws_size;
  const float* x    = (const float*)d_in[0];
  const float* memp = (const float*)d_in[1];
  const float* pqk1 = (const float*)d_in[2];
  const float* pqk2 = (const float*)d_in[3];
  const float* ip_w = (const float*)d_in[4];
  const float* ip_b = (const float*)d_in[5];
  const float* mp_w = (const float*)d_in[6];
  const float* mp_b = (const float*)d_in[7];
  const float* ln1g = (const float*)d_in[8];
  const float* ln1b = (const float*)d_in[9];
  const float* ln2g = (const float*)d_in[10];
  const float* ln2b = (const float*)d_in[11];
  const float* ln3g = (const float*)d_in[12];
  const float* ln3b = (const float*)d_in[13];
  const float* a1qw = (const float*)d_in[14];
  const float* a1qc = (const float*)d_in[15];
  const float* a1kw = (const float*)d_in[16];
  const float* a1kc = (const float*)d_in[17];
  const float* a1vw = (const float*)d_in[18];
  const float* a1vc = (const float*)d_in[19];
  const float* a1ow = (const float*)d_in[20];
  const float* a1pw = (const float*)d_in[21];
  const float* a2qw = (const float*)d_in[22];
  const float* a2qc = (const float*)d_in[23];
  const float* a2kw = (const float*)d_in[24];
  const float* a2kc = (const float*)d_in[25];
  const float* a2vw = (const float*)d_in[26];
  const float* a2vc = (const float*)d_in[27];
  const float* a2ow = (const float*)d_in[28];
  const float* a2pw = (const float*)d_in[29];
  const float* l1w  = (const float*)d_in[30];
  const float* l2w  = (const float*)d_in[31];

  float* outp = (float*)d_out;
  float* qk1o = outp + 4194304;    // [4][4][1024][1024]
  float* qk2o = outp + 20971520;

  const size_t MB = 1024 * 1024;
  char* W = (char*)d_ws;
  float* xs   = (float*)(W);             // 16MB f32 [4][1024w][1024h]
  u16* msb    = (u16*)(W + 16 * MB);     // 8MB bf16
  u16* xln    = (u16*)(W + 24 * MB);     // 8MB
  u16* QKVraw = (u16*)(W + 32 * MB);     // 24MB [4096][3072]
  u16* Qc     = (u16*)(W + 56 * MB);     // 8MB
  u16* Kc     = (u16*)(W + 64 * MB);     // 8MB
  u16* Vt     = (u16*)(W + 72 * MB);     // 8MB  [16][256][1024]
  u16* P      = (u16*)(W + 80 * MB);     // 32MB [16][1024][1024]
  u16* Am     = (u16*)(W + 112 * MB);    // 8MB
  u16* wqkv1  = (u16*)(W + 120 * MB);    // 6MB [3072][1024]
  u16* wqkv2  = (u16*)(W + 126 * MB);    // 6MB
  u16* wo1    = (u16*)(W + 132 * MB);    // 2MB
  u16* wo2    = (u16*)(W + 134 * MB);    // 2MB
  u16* wl1    = (u16*)(W + 136 * MB);    // 4MB [2048][1024]
  u16* wl2    = (u16*)(W + 140 * MB);    // 4MB [1024][2048]
  u16* pwt1   = (u16*)(W + 144 * MB);    // 0.5MB [1024][256]
  u16* pwt2   = (u16*)(W + 144 * MB + 512 * 1024);
  u16* H1     = QKVraw;                  // 16MB overlay (dead in FFN)

  CastJobs J;
  J.s[0] = a1qw; J.d[0] = wqkv1;
  J.s[1] = a1kw; J.d[1] = wqkv1 + 1048576;
  J.s[2] = a1vw; J.d[2] = wqkv1 + 2097152;
  J.s[3] = a2qw; J.d[3] = wqkv2;
  J.s[4] = a2kw; J.d[4] = wqkv2 + 1048576;
  J.s[5] = a2vw; J.d[5] = wqkv2 + 2097152;
  J.s[6] = a1ow; J.d[6] = wo1;
  J.s[7] = a2ow; J.d[7] = wo2;
  J.s[8] = l1w;            J.d[8] = wl1;
  J.s[9] = l1w + 1048576;  J.d[9] = wl1 + 1048576;
  J.s[10] = l2w;           J.d[10] = wl2;
  J.s[11] = l2w + 1048576; J.d[11] = wl2 + 1048576;
  cast12_kernel<<<dim3(1024, 12), 256, 0, stream>>>(J);
  pwt_kernel<<<dim3(32, 8, 1), dim3(32, 32), 0, stream>>>(a1pw, pwt1);
  pwt_kernel<<<dim3(32, 8, 1), dim3(32, 32), 0, stream>>>(a2pw, pwt2);

  // input projections: DMA-staged (global_load_lds) read path
  proj4_kernel<<<dim3(64, 4, 8), 256, 0, stream>>>(
      x, memp, ip_w, ip_b, mp_w, mp_b, xs, msb);

  // attention 1 (self): q and kv both from LN1(xs)
  ln_kernel<<<4096, 256, 0, stream>>>(xs, ln1g, ln1b, xln);
  run_attn(stream, xs, xln, xln, 1 << 30, QKVraw, Qc, Kc, Vt, P, Am,
           wqkv1, wo1, pwt1, a1qc, a1kc, a1vc, pqk1, qk1o);

  // attention 2 (cross): q from LN2(xs), kv from ms
  ln_kernel<<<4096, 256, 0, stream>>>(xs, ln2g, ln2b, xln);
  run_attn(stream, xs, xln, msb, 1024, QKVraw, Qc, Kc, Vt, P, Am,
           wqkv2, wo2, pwt2, a2qc, a2kc, a2vc, pqk2, qk2o);

  // FFN
  ln_kernel<<<4096, 256, 0, stream>>>(xs, ln3g, ln3b, xln);
  gemm_t<EPI_RELU2, false, 128><<<dim3(16, 32, 1), dim3(512), 0, stream>>>(
      xln, xln, 1 << 30, 0, 0, 1024, nullptr, 0,
      wl1, 0, 0, 1024, nullptr, 0, 0, 0,
      1024, 0, H1, 0, 0, 2048, nullptr, 0, 0, 1.f);
  gemm_t<EPI_ADDF32, false, 64><<<dim3(16, 32, 1), dim3(256), 0, stream>>>(
      H1, H1, 1 << 30, 0, 0, 2048, nullptr, 0,
      wl2, 0, 0, 2048, nullptr, 0, 0, 0,
      2048, 0, xs, 0, 0, 1024, nullptr, 0, 0, 1.f);

  // final transpose to out[b][1][bins][w]
  tout_kernel<<<dim3(32, 32, 4), dim3(32, 32), 0, stream>>>(xs, outp);
}

// Round 12
// 463.636 us; speedup vs baseline: 1.0699x; 1.0438x over previous
//
#include <hip/hip_runtime.h>
#include <stdint.h>

typedef unsigned short u16;
typedef __bf16 bfv8 __attribute__((ext_vector_type(8)));
typedef float f32x4 __attribute__((ext_vector_type(4)));
typedef unsigned short u16x8 __attribute__((ext_vector_type(8)));

#define DI __device__ __forceinline__

DI u16 f2bf(float f) {
  union { float f; unsigned u; } c; c.f = f;
  unsigned r = c.u + 0x7FFFu + ((c.u >> 16) & 1u);
  return (u16)(r >> 16);
}
DI float bf2f(u16 b) {
  union { unsigned u; float f; } c; c.u = ((unsigned)b) << 16;
  return c.f;
}

enum { EPI_BF16 = 0, EPI_RELU2 = 1, EPI_ADDF32 = 2, EPI_QK = 3, EPI_TOUT = 4 };

#define GLDS(g, l)                                                              \
  __builtin_amdgcn_global_load_lds((const __attribute__((address_space(1))) void*)(g), \
                                   (__attribute__((address_space(3))) void*)(l), 16, 0, 0)

#define VMCNT_BAR(N)                                        \
  do {                                                      \
    asm volatile("s_waitcnt vmcnt(" #N ")" ::: "memory");   \
    __builtin_amdgcn_sched_barrier(0);                      \
    __builtin_amdgcn_s_barrier();                           \
    __builtin_amdgcn_sched_barrier(0);                      \
  } while (0)

#define BAR_ONLY()                                          \
  do {                                                      \
    __builtin_amdgcn_sched_barrier(0);                      \
    __builtin_amdgcn_s_barrier();                           \
    __builtin_amdgcn_sched_barrier(0);                      \
  } while (0)

// C[m,n] = sum_k A[m,k]*B[n,k]. Tile 128x128, BK=64, 512 thr (8 waves 2Mx4N),
// 2-stage double-buffered LDS (64 KB -> 2 blocks/CU) + counted vmcnt(4) + setprio.
// Round-8-proven configuration. EPI_TOUT: residual add from `extra` (xs) then
// transposed store to out[b][h][w] (fuses the final transpose kernel).
template <int EPI, bool KSPLIT>
__global__ __launch_bounds__(512, 4) void gemm128(
    const u16* __restrict__ Aq, const u16* __restrict__ Akv, int asplit,
    long a1q, long a1r, int lda1,
    const u16* __restrict__ A2, int lda2,
    const u16* __restrict__ B1, long b1q, long b1r, int ldb1,
    const u16* __restrict__ B2, long b2q, long b2r, int ldb2,
    int K, int ksp,
    void* __restrict__ Cv, long cq, long cr, int ldc,
    const float* __restrict__ extra, long eq, int lde,
    float scale)
{
  constexpr int SS = 16384;
  __shared__ __align__(16) u16 lds[2 * SS];   // 64 KB
  const int tid = threadIdx.x;
  const int wid = tid >> 6, lane = tid & 63;

  const int gx = gridDim.x, gy = gridDim.y;
  const int nwg = gx * gy * (int)gridDim.z;
  const int flat = blockIdx.x + gx * (blockIdx.y + gy * blockIdx.z);
  const int q = nwg >> 3, r = nwg & 7;
  const int xcd = flat & 7, idx = flat >> 3;
  const int wg = (xcd < r ? xcd * (q + 1) : r * (q + 1) + (xcd - r) * q) + idx;
  const int bx = wg % gx;
  const int tmp = wg / gx;
  const int by = tmp % gy;
  const int bz = tmp / gy;

  const long zq = bz >> 2, zr = bz & 3;
  const int m0 = by * 128, n0 = bx * 128;
  const u16* Ab = ((n0 >= asplit) ? Akv : Aq) + zq * a1q + zr * a1r;
  const u16* Bb = B1 + zq * b1q + zr * b1r;
  const u16* B2b = KSPLIT ? (B2 + zq * b2q + zr * b2r) : (const u16*)nullptr;
  const int wm = (wid >> 2) * 64, wn = (wid & 3) * 32;
  const int fr = lane & 15, fq = lane >> 4;

  f32x4 acc[4][2];
#pragma unroll
  for (int i = 0; i < 4; ++i)
#pragma unroll
    for (int j = 0; j < 2; ++j)
      acc[i][j] = (f32x4){0.f, 0.f, 0.f, 0.f};

  const int nt = K >> 6;

  auto STAGE = [&](int tt, int sb) {
    const int k0 = tt << 6;
    u16* Ld = &lds[sb * SS];
    const u16* Asrc; int la; const u16* Bsrc; int lb;
    if (!KSPLIT || k0 < ksp) { Asrc = Ab + k0; la = lda1; Bsrc = Bb + k0; lb = ldb1; }
    else { Asrc = A2 + (k0 - ksp); la = lda2; Bsrc = B2b + (k0 - ksp); lb = ldb2; }
#pragma unroll
    for (int l = 0; l < 2; ++l) {
      int idx2 = (l << 9) + tid;
      int row = idx2 >> 3;
      int sc = ((idx2 & 7) ^ (row & 7)) << 3;
      GLDS(Asrc + (size_t)(m0 + row) * la + sc,
           Ld + (((l << 3) + wid) << 9));
    }
#pragma unroll
    for (int l = 0; l < 2; ++l) {
      int idx2 = (l << 9) + tid;
      int row = idx2 >> 3;
      int sc = ((idx2 & 7) ^ (row & 7)) << 3;
      GLDS(Bsrc + (size_t)(n0 + row) * lb + sc,
           Ld + 8192 + (((l << 3) + wid) << 9));
    }
  };

  auto COMPUTE = [&](int cb) {
    const u16* As = &lds[cb * SS];
    const u16* Bs = As + 8192;
#pragma unroll
    for (int ks = 0; ks < 2; ++ks) {
      bfv8 av[4];
#pragma unroll
      for (int i = 0; i < 4; ++i) {
        int ra = wm + i * 16 + fr;
        int ca = (((ks << 2) + fq) ^ (ra & 7)) << 3;
        av[i] = *(const bfv8*)&As[(ra << 6) + ca];
      }
      bfv8 bv[2];
#pragma unroll
      for (int j = 0; j < 2; ++j) {
        int rb = wn + (j << 4) + fr;
        int cb2 = (((ks << 2) + fq) ^ (rb & 7)) << 3;
        bv[j] = *(const bfv8*)&Bs[(rb << 6) + cb2];
      }
      __builtin_amdgcn_s_setprio(1);
#pragma unroll
      for (int i = 0; i < 4; ++i) {
        acc[i][0] = __builtin_amdgcn_mfma_f32_16x16x32_bf16(av[i], bv[0], acc[i][0], 0, 0, 0);
        acc[i][1] = __builtin_amdgcn_mfma_f32_16x16x32_bf16(av[i], bv[1], acc[i][1], 0, 0, 0);
      }
      __builtin_amdgcn_s_setprio(0);
    }
  };

  STAGE(0, 0);
  STAGE(1, 1);
  VMCNT_BAR(4);
  for (int t = 0; t < nt; ++t) {
    COMPUTE(t & 1);
    BAR_ONLY();
    if (t + 2 < nt) {
      STAGE(t + 2, t & 1);
      VMCNT_BAR(4);
    } else if (t + 1 < nt) {
      VMCNT_BAR(0);
    }
  }

  if constexpr (EPI == EPI_BF16 || EPI == EPI_RELU2) {
    u16* Cb = (u16*)Cv + zq * cq + zr * cr;
#pragma unroll
    for (int i = 0; i < 4; ++i)
#pragma unroll
      for (int j = 0; j < 2; ++j)
#pragma unroll
        for (int r2 = 0; r2 < 4; ++r2) {
          int row = m0 + wm + i * 16 + (fq << 2) + r2;
          int col = n0 + wn + j * 16 + fr;
          float v = acc[i][j][r2];
          if constexpr (EPI == EPI_RELU2) { v = fmaxf(v, 0.f); v = v * v; }
          Cb[(size_t)row * ldc + col] = f2bf(v);
        }
  } else if constexpr (EPI == EPI_ADDF32) {
    float* Cb = (float*)Cv + zq * cq + zr * cr;
#pragma unroll
    for (int i = 0; i < 4; ++i)
#pragma unroll
      for (int j = 0; j < 2; ++j)
#pragma unroll
        for (int r2 = 0; r2 < 4; ++r2) {
          int row = m0 + wm + i * 16 + (fq << 2) + r2;
          int col = n0 + wn + j * 16 + fr;
          Cb[(size_t)row * ldc + col] += acc[i][j][r2];
        }
  } else if constexpr (EPI == EPI_TOUT) {
    // val = xs[row][col] + acc; out[b][col][row&1023] = val  (b = row>>10)
    float* Ob = (float*)Cv;
    const float* Xb = extra;
#pragma unroll
    for (int i = 0; i < 4; ++i)
#pragma unroll
      for (int j = 0; j < 2; ++j)
#pragma unroll
        for (int r2 = 0; r2 < 4; ++r2) {
          int row = m0 + wm + i * 16 + (fq << 2) + r2;
          int col = n0 + wn + j * 16 + fr;
          float v = Xb[(size_t)row * lde + col] + acc[i][j][r2];
          Ob[(((size_t)(row >> 10) << 10) + col) * 1024 + (row & 1023)] = v;
        }
  } else {  // EPI_QK
    float* Cb = (float*)Cv + zq * cq + zr * cr;
    const float* Eb = extra + (size_t)bz * eq;
#pragma unroll
    for (int i = 0; i < 4; ++i)
#pragma unroll
      for (int j = 0; j < 2; ++j)
#pragma unroll
        for (int r2 = 0; r2 < 4; ++r2) {
          int row = m0 + wm + i * 16 + (fq << 2) + r2;
          int col = n0 + wn + j * 16 + fr;
          Cb[(size_t)row * ldc + col] = acc[i][j][r2] * scale + Eb[(size_t)row * lde + col];
        }
  }
}

// Input projection via global_load_lds DMA staging.
__global__ __launch_bounds__(256) void proj4_kernel(const float* __restrict__ x,
                                                    const float* __restrict__ memp,
                                                    const float* __restrict__ ipw,
                                                    const float* __restrict__ ipb,
                                                    const float* __restrict__ mpw,
                                                    const float* __restrict__ mpb,
                                                    float* __restrict__ xs,
                                                    u16* __restrict__ msb)
{
  __shared__ __align__(16) float sbuf[2][16][256];   // 32 KB
  const int t = threadIdx.x;
  const int wid = t >> 6, lane = t & 63;
  const int task = blockIdx.z >> 2;
  const int b = blockIdx.z & 3;
  const int h0 = blockIdx.x << 4;
  const int w0 = blockIdx.y << 8;
  const float* src = task ? memp : x;
  const float* w8 = task ? mpw : ipw;
  const float bias = task ? mpb[0] : ipb[0];
  const int crot = (blockIdx.x + blockIdx.y + blockIdx.z) & 7;
  float wr[8];
#pragma unroll
  for (int j = 0; j < 8; ++j) wr[j] = w8[(j + crot) & 7];
  float acc[16];
#pragma unroll
  for (int h = 0; h < 16; ++h) acc[h] = bias;
  const size_t bbase = ((size_t)b * 8) << 20;

  auto STAGE_C = [&](int i, int sb) {
    const int c = (i + crot) & 7;
    const float* g = src + bbase + ((size_t)c << 20) + (size_t)h0 * 1024 + w0 + (lane << 2);
#pragma unroll
    for (int l = 0; l < 4; ++l) {
      int row = (wid << 2) + l;
      GLDS(g + (size_t)row * 1024, &sbuf[sb][row][0]);
    }
  };

  STAGE_C(0, 0);
  STAGE_C(1, 1);
#pragma unroll
  for (int i = 0; i < 8; ++i) {
    if (i < 7) VMCNT_BAR(4); else VMCNT_BAR(0);
    {
      const float wc = wr[i];
      const int sb = i & 1;
#pragma unroll
      for (int h = 0; h < 16; ++h)
        acc[h] += sbuf[sb][h][t] * wc;
    }
    BAR_ONLY();
    if (i + 2 < 8) STAGE_C(i + 2, i & 1);
  }

  if (task) {
    u16* d = &msb[((size_t)b * 1024 + w0 + t) * 1024 + h0];
    u16x8 o0, o1;
#pragma unroll
    for (int h = 0; h < 8; ++h) { o0[h] = f2bf(acc[h]); o1[h] = f2bf(acc[h + 8]); }
    *(u16x8*)&d[0] = o0;
    *(u16x8*)&d[8] = o1;
  } else {
    float* d = &xs[((size_t)b * 1024 + w0 + t) * 1024 + h0];
#pragma unroll
    for (int p = 0; p < 4; ++p) {
      f32x4 v = {acc[p * 4], acc[p * 4 + 1], acc[p * 4 + 2], acc[p * 4 + 3]};
      *(f32x4*)&d[p * 4] = v;
    }
  }
}

// LayerNorm over 1024, f32 in -> bf16 out. one block per row.
__global__ __launch_bounds__(256) void ln_kernel(const float* __restrict__ x,
                                                 const float* __restrict__ g,
                                                 const float* __restrict__ b,
                                                 u16* __restrict__ out)
{
  int row = blockIdx.x, tid = threadIdx.x;
  float4 v = ((const float4*)(x + (size_t)row * 1024))[tid];
  float s = v.x + v.y + v.z + v.w;
  float s2 = v.x * v.x + v.y * v.y + v.z * v.z + v.w * v.w;
#pragma unroll
  for (int o = 32; o; o >>= 1) { s += __shfl_down(s, o); s2 += __shfl_down(s2, o); }
  __shared__ float rs[4], rs2[4];
  int wid = tid >> 6, lane = tid & 63;
  if (lane == 0) { rs[wid] = s; rs2[wid] = s2; }
  __syncthreads();
  s = rs[0] + rs[1] + rs[2] + rs[3];
  s2 = rs2[0] + rs2[1] + rs2[2] + rs2[3];
  float mean = s * (1.f / 1024.f);
  float var = s2 * (1.f / 1024.f) - mean * mean;
  float rstd = rsqrtf(var + 1e-5f);
  float4 gv = ((const float4*)g)[tid];
  float4 bv = ((const float4*)b)[tid];
  ushort4 o;
  o.x = f2bf((v.x - mean) * rstd * gv.x + bv.x);
  o.y = f2bf((v.y - mean) * rstd * gv.y + bv.y);
  o.z = f2bf((v.z - mean) * rstd * gv.z + bv.z);
  o.w = f2bf((v.w - mean) * rstd * gv.w + bv.w);
  ((ushort4*)out)[(size_t)row * 256 + tid] = o;
}

// depthwise conv k=3 pad=1 along t for Q (sel=0) and K (sel=1) from fused QKV buffer.
__global__ __launch_bounds__(128) void dwconv_qk_kernel(const u16* __restrict__ qkv,
                                                        const float* __restrict__ qc,
                                                        const float* __restrict__ kc,
                                                        u16* __restrict__ Qc,
                                                        u16* __restrict__ Kc)
{
  int sel = blockIdx.y;
  int row = blockIdx.x;     // b*1024 + t
  int t = row & 1023;
  int c0 = threadIdx.x * 8;
  const u16* r0 = qkv + (size_t)row * 3072 + (sel << 10) + c0;
  const float* wc = sel ? kc : qc;
  u16* dst = (sel ? Kc : Qc) + (size_t)row * 1024 + c0;
  u16x8 zv = {0, 0, 0, 0, 0, 0, 0, 0};
  u16x8 xm = zv, xp = zv;
  if (t > 0) xm = *(const u16x8*)(r0 - 3072);
  u16x8 xc = *(const u16x8*)r0;
  if (t < 1023) xp = *(const u16x8*)(r0 + 3072);
  u16x8 o;
#pragma unroll
  for (int j = 0; j < 8; ++j) {
    int c = c0 + j;
    float v = bf2f(xm[j]) * wc[c * 3 + 0] + bf2f(xc[j]) * wc[c * 3 + 1] + bf2f(xp[j]) * wc[c * 3 + 2];
    o[j] = f2bf(v);
  }
  *(u16x8*)dst = o;
}

// depthwise conv + transposed store for V: out[(b*4+c/256)][c%256][t] from qkv col 2048+c
__global__ __launch_bounds__(1024) void dwconv_t_kernel(const u16* __restrict__ qkv,
                                                        const float* __restrict__ wc,
                                                        u16* __restrict__ out)
{
  __shared__ float tile[32][33];
  int b = blockIdx.z;
  int t = blockIdx.x * 32 + threadIdx.y;
  int c = blockIdx.y * 32 + threadIdx.x;
  size_t base = ((size_t)b * 1024 + t) * 3072 + 2048 + c;
  float xm = (t > 0) ? bf2f(qkv[base - 3072]) : 0.f;
  float xc = bf2f(qkv[base]);
  float xp = (t < 1023) ? bf2f(qkv[base + 3072]) : 0.f;
  tile[threadIdx.y][threadIdx.x] = xm * wc[c * 3 + 0] + xc * wc[c * 3 + 1] + xp * wc[c * 3 + 2];
  __syncthreads();
  int c2 = blockIdx.y * 32 + threadIdx.y;
  int t2 = blockIdx.x * 32 + threadIdx.x;
  int z = b * 4 + (c2 >> 8);
  out[((size_t)z * 256 + (c2 & 255)) * 1024 + t2] = f2bf(tile[threadIdx.x][threadIdx.y]);
}

// wave-per-row softmax over 1024: 16 rows/block, no LDS, no block barriers.
// Each lane processes 16 elements (4x f32x4 at i*256 + lane*4).
__global__ __launch_bounds__(1024) void softmax_kernel(const float* __restrict__ qk,
                                                       u16* __restrict__ P)
{
  const int wv = threadIdx.x >> 6, lane = threadIdx.x & 63;
  const size_t row = (size_t)blockIdx.x * 16 + wv;
  const float* src = &qk[row * 1024];
  f32x4 v[4];
#pragma unroll
  for (int i = 0; i < 4; ++i) v[i] = *(const f32x4*)&src[i * 256 + lane * 4];
  float m = v[0].x;
#pragma unroll
  for (int i = 0; i < 4; ++i)
    m = fmaxf(m, fmaxf(fmaxf(v[i].x, v[i].y), fmaxf(v[i].z, v[i].w)));
#pragma unroll
  for (int o = 32; o; o >>= 1) m = fmaxf(m, __shfl_xor(m, o));
  float e[4][4];
  float s = 0.f;
#pragma unroll
  for (int i = 0; i < 4; ++i) {
    e[i][0] = __expf(v[i].x - m); e[i][1] = __expf(v[i].y - m);
    e[i][2] = __expf(v[i].z - m); e[i][3] = __expf(v[i].w - m);
    s += e[i][0] + e[i][1] + e[i][2] + e[i][3];
  }
#pragma unroll
  for (int o = 32; o; o >>= 1) s += __shfl_xor(s, o);
  float rinv = 1.f / s;
  u16* dst = &P[row * 1024];
#pragma unroll
  for (int i = 0; i < 4; ++i) {
    ushort4 o;
    o.x = f2bf(e[i][0] * rinv); o.y = f2bf(e[i][1] * rinv);
    o.z = f2bf(e[i][2] * rinv); o.w = f2bf(e[i][3] * rinv);
    *(ushort4*)&dst[i * 256 + lane * 4] = o;
  }
}

// 12 fused f32->bf16 casts of 1M elements each (weight prep, one launch)
struct CastJobs { const float* s[12]; u16* d[12]; };
__global__ __launch_bounds__(256) void cast12_kernel(CastJobs J)
{
  int j = blockIdx.y;
  int i = blockIdx.x * 256 + threadIdx.x;   // 262144 float4 per job
  float4 v = ((const float4*)J.s[j])[i];
  ushort4 o;
  o.x = f2bf(v.x); o.y = f2bf(v.y); o.z = f2bf(v.z); o.w = f2bf(v.w);
  ((ushort4*)J.d[j])[i] = o;
}

// pw [256][1024] f32 -> pwT [1024][256] bf16
__global__ __launch_bounds__(1024) void pwt_kernel(const float* __restrict__ pw,
                                                   u16* __restrict__ pwT)
{
  __shared__ float tile[32][33];
  int d = blockIdx.y * 32 + threadIdx.y;
  int t = blockIdx.x * 32 + threadIdx.x;
  tile[threadIdx.y][threadIdx.x] = pw[(size_t)d * 1024 + t];
  __syncthreads();
  int t2 = blockIdx.x * 32 + threadIdx.y;
  int d2 = blockIdx.y * 32 + threadIdx.x;
  pwT[(size_t)t2 * 256 + d2] = f2bf(tile[threadIdx.x][threadIdx.y]);
}

static void run_attn(hipStream_t stream, float* xs, const u16* qsrc, const u16* kvsrc, int asplit,
                     u16* QKVraw, u16* Qc, u16* Kc, u16* Vt, u16* P, u16* Am,
                     const u16* wqkv, const u16* wo, const u16* pwt,
                     const float* qc, const float* kc, const float* vc,
                     const float* prevqk, float* qko)
{
  dim3 blk(512);
  // fused QKV projection: M=4096, N=3072, K=1024. 768 blocks @ 2/CU.
  gemm128<EPI_BF16, false><<<dim3(24, 32, 1), blk, 0, stream>>>(
      qsrc, kvsrc, asplit, 0, 0, 1024, nullptr, 0,
      wqkv, 0, 0, 1024, nullptr, 0, 0, 0,
      1024, 0, QKVraw, 0, 0, 3072, nullptr, 0, 0, 1.f);
  dwconv_qk_kernel<<<dim3(4096, 2), 128, 0, stream>>>(QKVraw, qc, kc, Qc, Kc);
  dwconv_t_kernel<<<dim3(32, 32, 4), dim3(32, 32), 0, stream>>>(QKVraw, vc, Vt);
  // qk = (Q Kt + pwT Qt)/32 + prev, K=512 split at 256. 1024 blocks.
  gemm128<EPI_QK, true><<<dim3(8, 8, 16), blk, 0, stream>>>(
      Qc, Qc, 1 << 30, 1048576, 256, 1024, pwt, 256,
      Kc, 1048576, 256, 1024, Qc, 1048576, 256, 1024,
      512, 256, qko, 4194304, 1048576, 1024, prevqk, 1048576, 1024, 0.03125f);
  softmax_kernel<<<1024, 1024, 0, stream>>>(qko, P);
  // PV: per z, [1024x1024]x[1024x256]. 256 blocks.
  gemm128<EPI_BF16, false><<<dim3(2, 8, 16), blk, 0, stream>>>(
      P, P, 1 << 30, 4194304, 1048576, 1024, nullptr, 0,
      Vt, 1048576, 262144, 1024, nullptr, 0, 0, 0,
      1024, 0, Am, 1048576, 256, 1024, nullptr, 0, 0, 1.f);
  // O-proj + residual add into xs (f32). 256 blocks.
  gemm128<EPI_ADDF32, false><<<dim3(8, 32, 1), blk, 0, stream>>>(
      Am, Am, 1 << 30, 0, 0, 1024, nullptr, 0,
      wo, 0, 0, 1024, nullptr, 0, 0, 0,
      1024, 0, xs, 0, 0, 1024, nullptr, 0, 0, 1.f);
}

extern "C" void kernel_launch(void* const* d_in, const int* in_sizes, int n_in,
                              void* d_out, int out_size, void* d_ws, size_t ws_size,
                              hipStream_t stream)
{
  (void)in_sizes; (void)n_in; (void)out_size; (void)ws_size;
  const float* x    = (const float*)d_in[0];
  const float* memp = (const float*)d_in[1];
  const float* pqk1 = (const float*)d_in[2];
  const float* pqk2 = (const float*)d_in[3];
  const float* ip_w = (const float*)d_in[4];
  const float* ip_b = (const float*)d_in[5];
  const float* mp_w = (const float*)d_in[6];
  const float* mp_b = (const float*)d_in[7];
  const float* ln1g = (const float*)d_in[8];
  const float* ln1b = (const float*)d_in[9];
  const float* ln2g = (const float*)d_in[10];
  const float* ln2b = (const float*)d_in[11];
  const float* ln3g = (const float*)d_in[12];
  const float* ln3b = (const float*)d_in[13];
  const float* a1qw = (const float*)d_in[14];
  const float* a1qc = (const float*)d_in[15];
  const float* a1kw = (const float*)d_in[16];
  const float* a1kc = (const float*)d_in[17];
  const float* a1vw = (const float*)d_in[18];
  const float* a1vc = (const float*)d_in[19];
  const float* a1ow = (const float*)d_in[20];
  const float* a1pw = (const float*)d_in[21];
  const float* a2qw = (const float*)d_in[22];
  const float* a2qc = (const float*)d_in[23];
  const float* a2kw = (const float*)d_in[24];
  const float* a2kc = (const float*)d_in[25];
  const float* a2vw = (const float*)d_in[26];
  const float* a2vc = (const float*)d_in[27];
  const float* a2ow = (const float*)d_in[28];
  const float* a2pw = (const float*)d_in[29];
  const float* l1w  = (const float*)d_in[30];
  const float* l2w  = (const float*)d_in[31];

  float* outp = (float*)d_out;
  float* qk1o = outp + 4194304;    // [4][4][1024][1024]
  float* qk2o = outp + 20971520;

  const size_t MB = 1024 * 1024;
  char* W = (char*)d_ws;
  float* xs   = (float*)(W);             // 16MB f32 [4][1024w][1024h]
  u16* msb    = (u16*)(W + 16 * MB);     // 8MB bf16
  u16* xln    = (u16*)(W + 24 * MB);     // 8MB
  u16* QKVraw = (u16*)(W + 32 * MB);     // 24MB [4096][3072]
  u16* Qc     = (u16*)(W + 56 * MB);     // 8MB
  u16* Kc     = (u16*)(W + 64 * MB);     // 8MB
  u16* Vt     = (u16*)(W + 72 * MB);     // 8MB  [16][256][1024]
  u16* P      = (u16*)(W + 80 * MB);     // 32MB [16][1024][1024]
  u16* Am     = (u16*)(W + 112 * MB);    // 8MB
  u16* wqkv1  = (u16*)(W + 120 * MB);    // 6MB [3072][1024]
  u16* wqkv2  = (u16*)(W + 126 * MB);    // 6MB
  u16* wo1    = (u16*)(W + 132 * MB);    // 2MB
  u16* wo2    = (u16*)(W + 134 * MB);    // 2MB
  u16* wl1    = (u16*)(W + 136 * MB);    // 4MB [2048][1024]
  u16* wl2    = (u16*)(W + 140 * MB);    // 4MB [1024][2048]
  u16* pwt1   = (u16*)(W + 144 * MB);    // 0.5MB [1024][256]
  u16* pwt2   = (u16*)(W + 144 * MB + 512 * 1024);
  u16* H1     = QKVraw;                  // 16MB overlay (dead in FFN)

  CastJobs J;
  J.s[0] = a1qw; J.d[0] = wqkv1;
  J.s[1] = a1kw; J.d[1] = wqkv1 + 1048576;
  J.s[2] = a1vw; J.d[2] = wqkv1 + 2097152;
  J.s[3] = a2qw; J.d[3] = wqkv2;
  J.s[4] = a2kw; J.d[4] = wqkv2 + 1048576;
  J.s[5] = a2vw; J.d[5] = wqkv2 + 2097152;
  J.s[6] = a1ow; J.d[6] = wo1;
  J.s[7] = a2ow; J.d[7] = wo2;
  J.s[8] = l1w;            J.d[8] = wl1;
  J.s[9] = l1w + 1048576;  J.d[9] = wl1 + 1048576;
  J.s[10] = l2w;           J.d[10] = wl2;
  J.s[11] = l2w + 1048576; J.d[11] = wl2 + 1048576;
  cast12_kernel<<<dim3(1024, 12), 256, 0, stream>>>(J);
  pwt_kernel<<<dim3(32, 8, 1), dim3(32, 32), 0, stream>>>(a1pw, pwt1);
  pwt_kernel<<<dim3(32, 8, 1), dim3(32, 32), 0, stream>>>(a2pw, pwt2);

  // input projections: DMA-staged (global_load_lds) read path
  proj4_kernel<<<dim3(64, 4, 8), 256, 0, stream>>>(
      x, memp, ip_w, ip_b, mp_w, mp_b, xs, msb);

  // attention 1 (self): q and kv both from LN1(xs)
  ln_kernel<<<4096, 256, 0, stream>>>(xs, ln1g, ln1b, xln);
  run_attn(stream, xs, xln, xln, 1 << 30, QKVraw, Qc, Kc, Vt, P, Am,
           wqkv1, wo1, pwt1, a1qc, a1kc, a1vc, pqk1, qk1o);

  // attention 2 (cross): q from LN2(xs), kv from ms
  ln_kernel<<<4096, 256, 0, stream>>>(xs, ln2g, ln2b, xln);
  run_attn(stream, xs, xln, msb, 1024, QKVraw, Qc, Kc, Vt, P, Am,
           wqkv2, wo2, pwt2, a2qc, a2kc, a2vc, pqk2, qk2o);

  // FFN
  ln_kernel<<<4096, 256, 0, stream>>>(xs, ln3g, ln3b, xln);
  gemm128<EPI_RELU2, false><<<dim3(16, 32, 1), dim3(512), 0, stream>>>(
      xln, xln, 1 << 30, 0, 0, 1024, nullptr, 0,
      wl1, 0, 0, 1024, nullptr, 0, 0, 0,
      1024, 0, H1, 0, 0, 2048, nullptr, 0, 0, 1.f);
  // FFN2 + residual + transposed store directly to out[b][1][bins][w]
  gemm128<EPI_TOUT, false><<<dim3(8, 32, 1), dim3(512), 0, stream>>>(
      H1, H1, 1 << 30, 0, 0, 2048, nullptr, 0,
      wl2, 0, 0, 2048, nullptr, 0, 0, 0,
      2048, 0, outp, 0, 0, 1024, xs, 0, 1024, 1.f);
}